// Round 11
// baseline (2103.401 us; speedup 1.0000x reference)
//
#include <hip/hip_runtime.h>

#define Tn 512
#define Bn 64
#define In 128
#define Hn 1024
#define GBn 16    // batch rows per group
#define NGn 4     // independent batch groups
#define NBLKn 64  // blocks per group (Hn / NCOLn)
#define NCOLn 16  // H columns per block
#define ROW64 (Hn / 4)  // u64 words per h-row (4 cols packed per u64)

typedef __attribute__((ext_vector_type(8))) short short8;
typedef __attribute__((ext_vector_type(4))) float f32x4;
typedef unsigned long long u64;
typedef unsigned int u32;

__device__ __forceinline__ short f2bf(float f) {
  u32 u = __builtin_bit_cast(u32, f);
  u32 r = u + 0x7FFFu + ((u >> 16) & 1u);  // RTNE
  return (short)(r >> 16);
}
__device__ __forceinline__ float sigm(float x) { return 1.f / (1.f + __expf(-x)); }
__device__ __forceinline__ float tanh_f(float x) {
  float ax = fabsf(x);
  float e = __expf(-2.f * ax);
  float t = (1.f - e) / (1.f + e);
  return x < 0.f ? -t : t;
}
__device__ __forceinline__ short8 cvt8(const float* p) {
  float4 a0 = *(const float4*)p;
  float4 a1 = *(const float4*)(p + 4);
  short8 w;
  w[0] = f2bf(a0.x); w[1] = f2bf(a0.y); w[2] = f2bf(a0.z); w[3] = f2bf(a0.w);
  w[4] = f2bf(a1.x); w[5] = f2bf(a1.y); w[6] = f2bf(a1.z); w[7] = f2bf(a1.w);
  return w;
}

// f32 -> bf16 bits, 8 per thread. Grid must cover n/8 exactly.
__global__ void __launch_bounds__(256) cvt_kernel(const float* __restrict__ x,
                                                  unsigned short* __restrict__ xb) {
  size_t idx = ((size_t)blockIdx.x * 256 + threadIdx.x) * 8;
  *(short8*)(xb + idx) = cvt8(x + idx);
}

// Wire: u64 = q0|q1<<12 (lo32), q2|q3<<12|tag<<24 (hi32); q = round(h*2048)
// 12-bit fixed; tag = (t%255)+1 (never 0 = memset; alias needs 510-step skew,
// impossible at <=1-step skew). 2-slot ping-pong, fire-and-forget atomic u64
// stores, consumers collectively poll the full slot. Overwrite safety:
// producer stores tag-(t+2) only after its step-(t+2) poll saw all tag-(t+1)
// words, which each consumer posts only after finishing its step-(t+1)
// reads (data dependency through the MFMA chain).
//
// THIS ROUND: mixed-gate B-packing. Wave wid owns cols hc*16+4*wid..+3 for
// ALL 4 gates: B-row n = rowsel -> (gate = n>>2, col = n&3). The MFMA output
// then holds i,f,g,o for (16 rows x 4 cols) within the wave; the pointwise
// is done in-register via 3 shfl_xor (dist 4/8/12) + selects. gates_s LDS,
// bias LDS and the bar_g barrier are GONE: one __syncthreads per step.
// h_lds is double-buffered (WAR across steps ordered by the barrier chain:
// a wave stages buf at t+2 only after passing bar(t+1), which all waves
// reach only after their step-t reads of that buf).
__global__ void __launch_bounds__(256, 1) lstm_kernel(
    const unsigned short* __restrict__ xb, const float* __restrict__ W_ih,
    const float* __restrict__ W_hh, const float* __restrict__ b_ih,
    const float* __restrict__ b_hh, unsigned short* __restrict__ hsb,
    u64* __restrict__ pp) {
  const int bid = blockIdx.x;
  const int grp = bid >> 6;   // batch group 0..3
  const int hc = bid & 63;    // H-chunk (16 cols each)
  const int tid = threadIdx.x;
  const int wid = tid >> 6;   // wave: cols hc*16+4*wid..+3 (all gates);
                              // stages rows 4*wid..4*wid+3
  const int lane = tid & 63;
  const int rowsel = lane & 15;
  const int k8 = (lane >> 4) * 8;
  const int gq = rowsel >> 2;  // this lane's gate
  const int cq = rowsel & 3;   // this lane's col within the wave's quad
  const int hi4 = (lane >> 4) * 4;  // batch-row base of C-fragment

  __shared__ unsigned short h_lds[2][GBn * Hn];  // 2 x 32 KB (double buffer)

  // --- weights -> registers: mixed-gate B-rows. One-time. ---
  const int wrow = gq * Hn + hc * NCOLn + wid * 4 + cq;  // gate-row in [0,4096)
  short8 whh[32];
#pragma unroll
  for (int kt = 0; kt < 32; ++kt)
    whh[kt] = cvt8(W_hh + (size_t)wrow * Hn + kt * 32 + k8);
  short8 wih[4];
#pragma unroll
  for (int kt = 0; kt < 4; ++kt)
    wih[kt] = cvt8(W_ih + (size_t)wrow * In + kt * 32 + k8);
  const float bias_r = b_ih[wrow] + b_hh[wrow];

  u64* ppg = pp + (size_t)grp * 2 * (GBn * ROW64);
  const unsigned short* xrow = xb + (size_t)(grp * GBn + rowsel) * (Tn * In);

  const int rswz = (rowsel & 7) << 4;
  const int rbase = rowsel * 2048 + k8 * 2;

  const bool gg0 = (gq == 0), gg1 = (gq == 1), gg2 = (gq == 2), gg3 = (gq == 3);

  float c_reg[4] = {0.f, 0.f, 0.f, 0.f};  // 4 batch rows (hi4..hi4+3), col cq

  // x fragments prefetched one step ahead (+k8 REQUIRED: A[m][k],
  // k = kt*32 + (lane>>4)*8 + j — round-8 bug class).
  short8 xa[4], xn[4];
#pragma unroll
  for (int kt = 0; kt < 4; ++kt)
    xa[kt] = *(const short8*)(xrow + k8 + kt * 32);

#pragma clang loop unroll(disable)
  for (int t = 0; t < Tn; ++t) {
    f32x4 acc[4];
#pragma unroll
    for (int q = 0; q < 4; ++q) acc[q] = (f32x4){0.f, 0.f, 0.f, 0.f};

    // x-part: register-only
#pragma unroll
    for (int kt = 0; kt < 4; ++kt)
      acc[kt] = __builtin_amdgcn_mfma_f32_16x16x32_bf16(xa[kt], wih[kt],
                                                        acc[kt], 0, 0, 0);
    // prefetch x for t+1
    {
      int tn = (t + 1 < Tn) ? t + 1 : t;
      const unsigned short* xp = xrow + (size_t)tn * In + k8;
#pragma unroll
      for (int kt = 0; kt < 4; ++kt) xn[kt] = *(const short8*)(xp + kt * 32);
    }

    const int hbuf = (t & 1) ^ 1;  // stage/read buffer for h(t-1)
    if (t > 0) {
      const u32 want = (u32)((t - 1) % 255) + 1;
      const u64* src64 = ppg + ((t - 1) & 1) * (GBn * ROW64);
      // wave stages rows 4*wid..4*wid+3; 16 u64/lane = full 4 rows
      u64 v[16];
      while (true) {
        bool okv = true;
#pragma unroll
        for (int j = 0; j < 16; ++j) {
          const u64* pl =
              src64 + (4 * wid + (j >> 2)) * ROW64 + (j & 3) * 64 + lane;
          v[j] = __hip_atomic_load(pl, __ATOMIC_RELAXED,
                                   __HIP_MEMORY_SCOPE_AGENT);
        }
#pragma unroll
        for (int j = 0; j < 16; ++j) okv = okv && ((u32)(v[j] >> 56) == want);
        if (__all(okv)) break;
        __builtin_amdgcn_s_sleep(1);
      }
      // unpack 12-bit fixed -> bf16 pairs; LDS write conflict-free b64,
      // XOR row-swizzle matching the fragment reads
#pragma unroll
      for (int j = 0; j < 16; ++j) {
        u32 lo = (u32)v[j], hi = (u32)(v[j] >> 32);
        float f0 = (float)(((int)(lo << 20)) >> 20) * 4.8828125e-4f;
        float f1 = (float)(((int)(lo << 8)) >> 20) * 4.8828125e-4f;
        float f2 = (float)(((int)(hi << 20)) >> 20) * 4.8828125e-4f;
        float f3 = (float)(((int)(hi << 8)) >> 20) * 4.8828125e-4f;
        u32 w01, w23;
        asm("v_cvt_pk_bf16_f32 %0, %1, %2" : "=v"(w01) : "v"(f0), "v"(f1));
        asm("v_cvt_pk_bf16_f32 %0, %1, %2" : "=v"(w23) : "v"(f2), "v"(f3));
        int row = 4 * wid + (j >> 2);
        int c4 = (j & 3) * 64 + lane;
        int byteoff = (row * 2048 + c4 * 8) ^ ((row & 7) << 4);
        *(u64*)((char*)h_lds[hbuf] + byteoff) = ((u64)w23 << 32) | (u64)w01;
      }
      __syncthreads();  // the ONLY barrier: h_lds[hbuf] staged

      // h-part MFMAs from LDS (full K per wave)
#pragma unroll
      for (int kt = 0; kt < 32; ++kt) {
        short8 a =
            *(const short8*)((char*)h_lds[hbuf] + ((rbase + kt * 64) ^ rswz));
        acc[kt & 3] = __builtin_amdgcn_mfma_f32_16x16x32_bf16(a, whh[kt],
                                                              acc[kt & 3], 0, 0, 0);
      }
    }

    f32x4 asum = (acc[0] + acc[1]) + (acc[2] + acc[3]);
    const u32 tag = (u32)(t % 255) + 1;

    // in-register pointwise: gather the 4 gates via xor-shuffles (4/8/12)
    float hv[4];
#pragma unroll
    for (int r = 0; r < 4; ++r) {
      float m = asum[r] + bias_r;
      float v1 = __shfl_xor(m, 4);
      float v2 = __shfl_xor(m, 8);
      float v3 = __shfl_xor(m, 12);
      // value of absolute gate q sits at shuffle-distance (gq^q)*4
      float iv = gg0 ? m : gg1 ? v1 : gg2 ? v2 : v3;
      float fv = gg1 ? m : gg0 ? v1 : gg3 ? v2 : v3;
      float gv = gg2 ? m : gg3 ? v1 : gg0 ? v2 : v3;
      float ov = gg3 ? m : gg2 ? v1 : gg1 ? v2 : v3;
      float ig = sigm(iv), fg = sigm(fv), og = sigm(ov), gt_ = tanh_f(gv);
      c_reg[r] = fg * c_reg[r] + ig * gt_;
      hv[r] = og * tanh_f(c_reg[r]);
    }

    // pack + store: pp tagged u64 (writer rowsel==0) and hs bf16 pairs
    // (writers rowsel 0,2). All lanes run the shuffles (uniform).
#pragma unroll
    for (int r = 0; r < 4; ++r) {
      int q12 = (int)rintf(hv[r] * 2048.f);
      q12 = q12 > 2047 ? 2047 : (q12 < -2048 ? -2048 : q12);
      u32 me = (u32)(q12 & 0xFFF) << (12 * (cq & 1));
      u32 m2 = me | __shfl_xor(me, 1);  // (q0|q1<<12) on c0/1, (q2|q3<<12) on c2/3
      u32 mo = __shfl_xor(m2, 2);       // the other pair's word
      u32 hb = (u32)(unsigned short)f2bf(hv[r]);
      u32 oth = __shfl_xor(hb, 1);
      if (rowsel == 0) {
        u64 wv = ((u64)(mo | (tag << 24)) << 32) | (u64)m2;
        __hip_atomic_store(
            ppg + (t & 1) * (GBn * ROW64) + (hi4 + r) * ROW64 + (hc * 4 + wid),
            wv, __ATOMIC_RELAXED, __HIP_MEMORY_SCOPE_AGENT);
      }
      if (gg0 && !(cq & 1)) {  // rowsel 0 or 2
        size_t hsidx = ((size_t)t * Bn + grp * GBn + hi4 + r) * Hn +
                       hc * NCOLn + wid * 4 + cq;
        *(u32*)(hsb + hsidx) = hb | (oth << 16);
      }
    }

#pragma unroll
    for (int kt = 0; kt < 4; ++kt) xa[kt] = xn[kt];
  }
}

// out[b][t][i] = hs[row=t*64+b][:] . fcw_b16[i][:] + fcb[i], via MFMA.
__global__ void __launch_bounds__(256) fc_mfma_kernel(
    const unsigned short* __restrict__ hsb, const unsigned short* __restrict__ fwb,
    const float* __restrict__ fcb, float* __restrict__ out) {
  const int wid = threadIdx.x >> 6;
  const int lane = threadIdx.x & 63;
  const int rowsel = lane & 15;
  const int k8 = (lane >> 4) * 8;
  const int r0 = blockIdx.x * 16;
  const int i0 = wid * 32;
  f32x4 acc0 = {0.f, 0.f, 0.f, 0.f}, acc1 = {0.f, 0.f, 0.f, 0.f};
  const unsigned short* hrow = hsb + (size_t)(r0 + rowsel) * Hn + k8;
  const unsigned short* w0 = fwb + (size_t)(i0 + rowsel) * Hn + k8;
  const unsigned short* w1 = w0 + 16 * Hn;
#pragma unroll 8
  for (int kt = 0; kt < 32; ++kt) {
    short8 a = *(const short8*)(hrow + kt * 32);
    short8 b0 = *(const short8*)(w0 + kt * 32);
    short8 b1 = *(const short8*)(w1 + kt * 32);
    acc0 = __builtin_amdgcn_mfma_f32_16x16x32_bf16(a, b0, acc0, 0, 0, 0);
    acc1 = __builtin_amdgcn_mfma_f32_16x16x32_bf16(a, b1, acc1, 0, 0, 0);
  }
  const int n = lane & 15;
  float bias0 = fcb[i0 + n], bias1 = fcb[i0 + 16 + n];
#pragma unroll
  for (int r = 0; r < 4; ++r) {
    int row = r0 + (lane >> 4) * 4 + r;  // row = t*64 + b
    float* op = out + ((size_t)(row & 63) * Tn + (row >> 6)) * In;
    op[i0 + n] = acc0[r] + bias0;
    op[i0 + 16 + n] = acc1[r] + bias1;
  }
}

extern "C" void kernel_launch(void* const* d_in, const int* in_sizes, int n_in,
                              void* d_out, int out_size, void* d_ws,
                              size_t ws_size, hipStream_t stream) {
  const float* x    = (const float*)d_in[0];
  const float* W_ih = (const float*)d_in[1];
  const float* W_hh = (const float*)d_in[2];
  const float* b_ih = (const float*)d_in[3];
  const float* b_hh = (const float*)d_in[4];
  const float* fc_w = (const float*)d_in[5];
  const float* fc_b = (const float*)d_in[6];
  float* out = (float*)d_out;

  const size_t hs_b = (size_t)Tn * Bn * Hn * 2;           // 64 MiB bf16 hs
  const size_t x_b  = (size_t)Bn * Tn * In * 2;           // 8 MiB bf16 x
  const size_t fw_b = (size_t)In * Hn * 2;                // 256 KiB bf16 fc_w
  const size_t pp_b = (size_t)NGn * 2 * GBn * ROW64 * 8;  // 256 KiB packed u64

  char* wsc = (char*)d_ws;
  unsigned short* hsb = (unsigned short*)wsc;
  unsigned short* xb  = (unsigned short*)(wsc + hs_b);
  unsigned short* fwb = (unsigned short*)(wsc + hs_b + x_b);
  u64* pp = (u64*)(wsc + hs_b + x_b + fw_b);

  (void)hipMemsetAsync(pp, 0, pp_b, stream);  // tags -> 0 (never matches)
  hipLaunchKernelGGL(cvt_kernel, dim3((Bn * Tn * In) / (256 * 8)), dim3(256),
                     0, stream, x, xb);
  hipLaunchKernelGGL(cvt_kernel, dim3((In * Hn) / (256 * 8)), dim3(256), 0,
                     stream, fc_w, fwb);
  hipLaunchKernelGGL(lstm_kernel, dim3(NGn * NBLKn), dim3(256), 0, stream, xb,
                     W_ih, W_hh, b_ih, b_hh, hsb, pp);
  hipLaunchKernelGGL(fc_mfma_kernel, dim3((Tn * Bn) / 16), dim3(256), 0,
                     stream, hsb, fwb, fc_b, out);
}

// Round 12
// 1613.623 us; speedup vs baseline: 1.3035x; 1.3035x over previous
//
#include <hip/hip_runtime.h>

#define Tn 512
#define Bn 64
#define In 128
#define Hn 1024
#define GBn 16    // batch rows per group
#define NGn 4     // independent batch groups
#define NBLKn 64  // blocks per group (Hn / NCOLn)
#define NCOLn 16  // H columns per block
#define ROW64 (Hn / 4)  // u64 words per h-row (4 cols packed per u64)

typedef __attribute__((ext_vector_type(8))) short short8;
typedef __attribute__((ext_vector_type(4))) float f32x4;
typedef unsigned long long u64;
typedef unsigned int u32;

__device__ __forceinline__ short f2bf(float f) {
  u32 u = __builtin_bit_cast(u32, f);
  u32 r = u + 0x7FFFu + ((u >> 16) & 1u);  // RTNE
  return (short)(r >> 16);
}
__device__ __forceinline__ float sigm(float x) { return 1.f / (1.f + __expf(-x)); }
__device__ __forceinline__ float tanh_f(float x) {
  float ax = fabsf(x);
  float e = __expf(-2.f * ax);
  float t = (1.f - e) / (1.f + e);
  return x < 0.f ? -t : t;
}
__device__ __forceinline__ short8 cvt8(const float* p) {
  float4 a0 = *(const float4*)p;
  float4 a1 = *(const float4*)(p + 4);
  short8 w;
  w[0] = f2bf(a0.x); w[1] = f2bf(a0.y); w[2] = f2bf(a0.z); w[3] = f2bf(a0.w);
  w[4] = f2bf(a1.x); w[5] = f2bf(a1.y); w[6] = f2bf(a1.z); w[7] = f2bf(a1.w);
  return w;
}

// f32 -> bf16 bits, 8 per thread. Grid must cover n/8 exactly.
__global__ void __launch_bounds__(256) cvt_kernel(const float* __restrict__ x,
                                                  unsigned short* __restrict__ xb) {
  size_t idx = ((size_t)blockIdx.x * 256 + threadIdx.x) * 8;
  *(short8*)(xb + idx) = cvt8(x + idx);
}

// Wire: u64 = q0|q1<<12 (lo32), q2|q3<<12|tag<<24 (hi32); q = round(h*2048)
// 12-bit fixed; tag = (t%255)+1 (never 0 = memset; alias needs 510-step skew,
// impossible at <=1-step skew). 2-slot ping-pong, fire-and-forget atomic u64
// stores, consumers poll-the-data (full slot). Overwrite safety: producer
// stores tag-(t+2) to slot s only after its step-(t+2) poll saw all
// tag-(t+1) words, which each consumer posts only after finishing its
// step-(t+1) reads of slot s (data dependency through the MFMA chain).
// This is round 9's proven structure (local optimum: K-split [r10] and
// single-barrier in-reg pointwise [r11] both regressed); only delta is
// u64 hs stores (half the store instructions, same coalescing).
__global__ void __launch_bounds__(256, 1) lstm_kernel(
    const unsigned short* __restrict__ xb, const float* __restrict__ W_ih,
    const float* __restrict__ W_hh, const float* __restrict__ b_ih,
    const float* __restrict__ b_hh, unsigned short* __restrict__ hsb,
    u64* __restrict__ pp) {
  const int bid = blockIdx.x;
  const int grp = bid >> 6;   // batch group 0..3
  const int hc = bid & 63;    // H-chunk (16 cols each)
  const int tid = threadIdx.x;
  const int wid = tid >> 6;   // wave = gate (i,f,g,o)
  const int lane = tid & 63;
  const int rowsel = lane & 15;
  const int k8 = (lane >> 4) * 8;

  __shared__ unsigned short h_lds[GBn * Hn];  // 32 KB staged h (swizzled)
  __shared__ float gates_s[4][16][17];
  __shared__ float bias_s[4][16];

  if (tid < 64) {
    int gg = tid >> 4, cc = tid & 15;
    int idx = gg * Hn + hc * NCOLn + cc;
    bias_s[gg][cc] = b_ih[idx] + b_hh[idx];
  }

  // --- weights -> registers (B-fragments, bf16 bits). One-time. ---
  const int wrow = wid * Hn + hc * NCOLn + rowsel;
  short8 whh[32];
#pragma unroll
  for (int kt = 0; kt < 32; ++kt)
    whh[kt] = cvt8(W_hh + (size_t)wrow * Hn + kt * 32 + k8);
  short8 wih[4];
#pragma unroll
  for (int kt = 0; kt < 4; ++kt)
    wih[kt] = cvt8(W_ih + (size_t)wrow * In + kt * 32 + k8);
  __syncthreads();

  u64* ppg = pp + (size_t)grp * 2 * (GBn * ROW64);
  const unsigned short* xrow = xb + (size_t)(grp * GBn + rowsel) * (Tn * In);

  const int prow = tid >> 4;  // pointwise row 0..15
  const int pcol = tid & 15;  // pointwise col within chunk
  float c_reg = 0.f;

  const int rswz = (rowsel & 7) << 4;
  const int rbase = rowsel * 2048 + k8 * 2;

  // x fragments prefetched one step ahead (+k8 REQUIRED: A[m][k],
  // k = kt*32 + (lane>>4)*8 + j — round-8 bug class).
  short8 xa[4], xn[4];
#pragma unroll
  for (int kt = 0; kt < 4; ++kt)
    xa[kt] = *(const short8*)(xrow + k8 + kt * 32);

#pragma clang loop unroll(disable)
  for (int t = 0; t < Tn; ++t) {
    f32x4 acc[4];
#pragma unroll
    for (int q = 0; q < 4; ++q) acc[q] = (f32x4){0.f, 0.f, 0.f, 0.f};

    // x-part: register-only
#pragma unroll
    for (int kt = 0; kt < 4; ++kt)
      acc[kt] = __builtin_amdgcn_mfma_f32_16x16x32_bf16(xa[kt], wih[kt],
                                                        acc[kt], 0, 0, 0);
    // prefetch x for t+1
    {
      int tn = (t + 1 < Tn) ? t + 1 : t;
      const unsigned short* xp = xrow + (size_t)tn * In + k8;
#pragma unroll
      for (int kt = 0; kt < 4; ++kt) xn[kt] = *(const short8*)(xp + kt * 32);
    }

    if (t > 0) {
      const u32 want = (u32)((t - 1) % 255) + 1;
      const u64* src64 = ppg + ((t - 1) & 1) * (GBn * ROW64);
      // wave wid covers rows 4*wid..4*wid+3; 16 u64/lane = full 4 rows
      u64 v[16];
      while (true) {
        bool okv = true;
#pragma unroll
        for (int j = 0; j < 16; ++j) {
          const u64* pl =
              src64 + (4 * wid + (j >> 2)) * ROW64 + (j & 3) * 64 + lane;
          v[j] = __hip_atomic_load(pl, __ATOMIC_RELAXED,
                                   __HIP_MEMORY_SCOPE_AGENT);
        }
#pragma unroll
        for (int j = 0; j < 16; ++j) okv = okv && ((u32)(v[j] >> 56) == want);
        if (__all(okv)) break;
        __builtin_amdgcn_s_sleep(1);
      }
      // unpack 12-bit fixed -> bf16 pairs; LDS write conflict-free b64,
      // XOR row-swizzle matching the fragment reads
#pragma unroll
      for (int j = 0; j < 16; ++j) {
        u32 lo = (u32)v[j], hi = (u32)(v[j] >> 32);
        float f0 = (float)(((int)(lo << 20)) >> 20) * 4.8828125e-4f;
        float f1 = (float)(((int)(lo << 8)) >> 20) * 4.8828125e-4f;
        float f2 = (float)(((int)(hi << 20)) >> 20) * 4.8828125e-4f;
        float f3 = (float)(((int)(hi << 8)) >> 20) * 4.8828125e-4f;
        u32 w01, w23;
        asm("v_cvt_pk_bf16_f32 %0, %1, %2" : "=v"(w01) : "v"(f0), "v"(f1));
        asm("v_cvt_pk_bf16_f32 %0, %1, %2" : "=v"(w23) : "v"(f2), "v"(f3));
        int row = 4 * wid + (j >> 2);
        int c4 = (j & 3) * 64 + lane;
        int byteoff = (row * 2048 + c4 * 8) ^ ((row & 7) << 4);
        *(u64*)((char*)h_lds + byteoff) = ((u64)w23 << 32) | (u64)w01;
      }
      __syncthreads();  // bar_h: h_lds ready

      // h-part MFMAs from LDS
#pragma unroll
      for (int kt = 0; kt < 32; ++kt) {
        short8 a = *(const short8*)((char*)h_lds + ((rbase + kt * 64) ^ rswz));
        acc[kt & 3] = __builtin_amdgcn_mfma_f32_16x16x32_bf16(a, whh[kt],
                                                              acc[kt & 3], 0, 0, 0);
      }
    }

    f32x4 asum = (acc[0] + acc[1]) + (acc[2] + acc[3]);
#pragma unroll
    for (int r = 0; r < 4; ++r)
      gates_s[wid][(lane >> 4) * 4 + r][lane & 15] = asum[r];
    __syncthreads();  // bar_g: gates ready (also protects h_lds reuse)

    // pointwise: thread owns (prow, pcol); c stays in a register
    float iv = gates_s[0][prow][pcol] + bias_s[0][pcol];
    float fv = gates_s[1][prow][pcol] + bias_s[1][pcol];
    float gv = gates_s[2][prow][pcol] + bias_s[2][pcol];
    float ov = gates_s[3][prow][pcol] + bias_s[3][pcol];
    float ig = sigm(iv), fg = sigm(fv), og = sigm(ov), gt = tanh_f(gv);
    c_reg = fg * c_reg + ig * gt;
    float hval = og * tanh_f(c_reg);

    // pack 4 cols -> one tagged u64; lanes pcol%4==0 store (fire-and-forget)
    int q12 = (int)rintf(hval * 2048.f);
    q12 = q12 > 2047 ? 2047 : (q12 < -2048 ? -2048 : q12);
    u32 me = (u32)(q12 & 0xFFF) << (12 * (pcol & 1));
    u32 m2 = me | __shfl_xor(me, 1);
    u32 mo = __shfl_xor(m2, 2);
    u32 tag = (u32)(t % 255) + 1;
    if ((pcol & 3) == 0) {
      u64 wv = ((u64)(mo | (tag << 24)) << 32) | (u64)m2;
      __hip_atomic_store(
          ppg + (t & 1) * (GBn * ROW64) + prow * ROW64 + ((hc * NCOLn + pcol) >> 2),
          wv, __ATOMIC_RELAXED, __HIP_MEMORY_SCOPE_AGENT);
    }
    // hs history for the FC pass: u64 (4 bf16 cols) from pcol%4==0 lanes
    u32 hb = (u32)(unsigned short)f2bf(hval);
    u32 other = __shfl_xor(hb, 1);
    u32 pairh = hb | (other << 16);        // cols (pcol&~1), +1
    u32 pair2 = __shfl_xor(pairh, 2);      // partner pair (pcol^2)
    if ((pcol & 3) == 0) {
      size_t hsidx =
          ((size_t)t * Bn + grp * GBn + prow) * Hn + hc * NCOLn + pcol;
      *(u64*)(hsb + hsidx) = ((u64)pair2 << 32) | (u64)pairh;
    }

#pragma unroll
    for (int kt = 0; kt < 4; ++kt) xa[kt] = xn[kt];
  }
}

// out[b][t][i] = hs[row=t*64+b][:] . fcw_b16[i][:] + fcb[i], via MFMA.
__global__ void __launch_bounds__(256) fc_mfma_kernel(
    const unsigned short* __restrict__ hsb, const unsigned short* __restrict__ fwb,
    const float* __restrict__ fcb, float* __restrict__ out) {
  const int wid = threadIdx.x >> 6;
  const int lane = threadIdx.x & 63;
  const int rowsel = lane & 15;
  const int k8 = (lane >> 4) * 8;
  const int r0 = blockIdx.x * 16;
  const int i0 = wid * 32;
  f32x4 acc0 = {0.f, 0.f, 0.f, 0.f}, acc1 = {0.f, 0.f, 0.f, 0.f};
  const unsigned short* hrow = hsb + (size_t)(r0 + rowsel) * Hn + k8;
  const unsigned short* w0 = fwb + (size_t)(i0 + rowsel) * Hn + k8;
  const unsigned short* w1 = w0 + 16 * Hn;
#pragma unroll 8
  for (int kt = 0; kt < 32; ++kt) {
    short8 a = *(const short8*)(hrow + kt * 32);
    short8 b0 = *(const short8*)(w0 + kt * 32);
    short8 b1 = *(const short8*)(w1 + kt * 32);
    acc0 = __builtin_amdgcn_mfma_f32_16x16x32_bf16(a, b0, acc0, 0, 0, 0);
    acc1 = __builtin_amdgcn_mfma_f32_16x16x32_bf16(a, b1, acc1, 0, 0, 0);
  }
  const int n = lane & 15;
  float bias0 = fcb[i0 + n], bias1 = fcb[i0 + 16 + n];
#pragma unroll
  for (int r = 0; r < 4; ++r) {
    int row = r0 + (lane >> 4) * 4 + r;  // row = t*64 + b
    float* op = out + ((size_t)(row & 63) * Tn + (row >> 6)) * In;
    op[i0 + n] = acc0[r] + bias0;
    op[i0 + 16 + n] = acc1[r] + bias1;
  }
}

extern "C" void kernel_launch(void* const* d_in, const int* in_sizes, int n_in,
                              void* d_out, int out_size, void* d_ws,
                              size_t ws_size, hipStream_t stream) {
  const float* x    = (const float*)d_in[0];
  const float* W_ih = (const float*)d_in[1];
  const float* W_hh = (const float*)d_in[2];
  const float* b_ih = (const float*)d_in[3];
  const float* b_hh = (const float*)d_in[4];
  const float* fc_w = (const float*)d_in[5];
  const float* fc_b = (const float*)d_in[6];
  float* out = (float*)d_out;

  const size_t hs_b = (size_t)Tn * Bn * Hn * 2;           // 64 MiB bf16 hs
  const size_t x_b  = (size_t)Bn * Tn * In * 2;           // 8 MiB bf16 x
  const size_t fw_b = (size_t)In * Hn * 2;                // 256 KiB bf16 fc_w
  const size_t pp_b = (size_t)NGn * 2 * GBn * ROW64 * 8;  // 256 KiB packed u64

  char* wsc = (char*)d_ws;
  unsigned short* hsb = (unsigned short*)wsc;
  unsigned short* xb  = (unsigned short*)(wsc + hs_b);
  unsigned short* fwb = (unsigned short*)(wsc + hs_b + x_b);
  u64* pp = (u64*)(wsc + hs_b + x_b + fw_b);

  (void)hipMemsetAsync(pp, 0, pp_b, stream);  // tags -> 0 (never matches)
  hipLaunchKernelGGL(cvt_kernel, dim3((Bn * Tn * In) / (256 * 8)), dim3(256),
                     0, stream, x, xb);
  hipLaunchKernelGGL(cvt_kernel, dim3((In * Hn) / (256 * 8)), dim3(256), 0,
                     stream, fc_w, fwb);
  hipLaunchKernelGGL(lstm_kernel, dim3(NGn * NBLKn), dim3(256), 0, stream, xb,
                     W_ih, W_hh, b_ih, b_hh, hsb, pp);
  hipLaunchKernelGGL(fc_mfma_kernel, dim3((Tn * Bn) / 16), dim3(256), 0,
                     stream, hsb, fwb, fc_b, out);
}